// Round 5
// baseline (54.338 us; speedup 1.0000x reference)
//
#include <hip/hip_runtime.h>
#include <hip/hip_bf16.h>

#define B 4
#define S 2048
#define D 512
#define P 16
#define NC 64   // chunks over sequence
#define CL 32   // chunk length = S/NC

// ---------------------------------------------------------------------------
// K1: fused prods+softmax+chunk-totals. Block = (b,c), 512 threads.
// Phase A (R1-verbatim butterfly): wave wv computes rows 4wv..4wv+3,
//   writes prods/w to LDS (for phase B) and to global (for k_apply).
// Phase B: totals; thread = d; x rows preloaded; prods via LDS float4
//   broadcast (same-address across lanes -> conflict-free).
// ---------------------------------------------------------------------------
__global__ __launch_bounds__(512) void k_pt(const float* __restrict__ x,
                                            const float* __restrict__ proxy,
                                            float* __restrict__ prods,
                                            float* __restrict__ wgt,
                                            float* __restrict__ T) {
    __shared__ float s_pr[CL][P];
    __shared__ float s_w [CL][P];

    const int c    = blockIdx.x & (NC - 1);
    const int b    = blockIdx.x >> 6;
    const int tid  = threadIdx.x;
    const int lane = tid & 63;
    const int wv   = tid >> 6;
    const int bs0  = b * S + c * CL;

    // ---------------- Phase A
#pragma unroll
    for (int r = 0; r < 4; ++r) {
        const int sl = wv * 4 + r;
        const int bs = bs0 + sl;
        const float* xr = x + (size_t)bs * D + lane * 8;
        float4 xa = *(const float4*)xr;
        float4 xb = *(const float4*)(xr + 4);

        float part[P];
#pragma unroll
        for (int p = 0; p < P; ++p) {
            const float* pr = proxy + p * D + lane * 8;
            float4 pa = *(const float4*)pr;
            float4 pb = *(const float4*)(pr + 4);
            part[p] = xa.x*pa.x + xa.y*pa.y + xa.z*pa.z + xa.w*pa.w
                    + xb.x*pb.x + xb.y*pb.y + xb.z*pb.z + xb.w*pb.w;
        }
#pragma unroll
        for (int p = 0; p < P; ++p) {
            float v = part[p];
#pragma unroll
            for (int off = 32; off > 0; off >>= 1) v += __shfl_xor(v, off);
            part[p] = v;
        }
        float m = part[0];
#pragma unroll
        for (int p = 1; p < P; ++p) m = fmaxf(m, part[p]);
        float e[P];
        float den = 0.f;
#pragma unroll
        for (int p = 0; p < P; ++p) { e[p] = __expf((part[p] - m) * 0.25f); den += e[p]; }
        float inv = 1.f / den;

        int lp = lane & 15;
        float myp = part[0], mye = e[0];
#pragma unroll
        for (int p = 1; p < P; ++p) {
            bool sel = (lp == p);
            myp = sel ? part[p] : myp;
            mye = sel ? e[p]    : mye;
        }
        if (lane < P) {
            float myw = mye * inv;
            s_pr[sl][lane] = myp;
            s_w [sl][lane] = myw;
            prods[(size_t)bs * P + lane] = myp;
            wgt  [(size_t)bs * P + lane] = myw;
        }
    }
    __syncthreads();

    // ---------------- Phase B: totals -> T[b,c,p,d]
    {
        const int d = tid;
        float xv[CL];
#pragma unroll
        for (int i = 0; i < CL; ++i) xv[i] = x[(size_t)(bs0 + i) * D + d];

        float acc[P];
#pragma unroll
        for (int p = 0; p < P; ++p) acc[p] = 0.f;

#pragma unroll
        for (int i = 0; i < CL; ++i) {
            float pr[P];
            const float4* sp = (const float4*)(&s_pr[i][0]);
            ((float4*)pr)[0] = sp[0];
            ((float4*)pr)[1] = sp[1];
            ((float4*)pr)[2] = sp[2];
            ((float4*)pr)[3] = sp[3];
#pragma unroll
            for (int p = 0; p < P; ++p) acc[p] = fmaf(pr[p], xv[i], acc[p]);
        }
        size_t tb = (size_t)blockIdx.x * (P * D) + d;
#pragma unroll
        for (int p = 0; p < P; ++p) T[tb + p * D] = acc[p];
    }
}

// ---------------------------------------------------------------------------
// K2: in-place exclusive prefix over chunks. Thread = (b,p,d).
// Full 64-element preload -> one latency round-trip.
// ---------------------------------------------------------------------------
__global__ __launch_bounds__(128) void k_scan(float* __restrict__ T) {
    int t = blockIdx.x * 128 + threadIdx.x;   // ((b*P+p)*D + d), 32768 total
    int d = t & (D - 1);
    int p = (t >> 9) & (P - 1);
    int b = t >> 13;
    size_t base = ((size_t)b * NC * P + p) * D + d;

    float v[NC];
#pragma unroll
    for (int c = 0; c < NC; ++c) v[c] = T[base + (size_t)c * (P * D)];

    float run = 0.f;
#pragma unroll
    for (int c = 0; c < NC; ++c) {
        T[base + (size_t)c * (P * D)] = run;
        run += v[c];
    }
}

// ---------------------------------------------------------------------------
// K3: apply. Block = (b,c,half), 256 threads, thread = d within half.
// R4-proven body + 32-row x preload.
// ---------------------------------------------------------------------------
__global__ __launch_bounds__(256) void k_apply(const float* __restrict__ x,
                                               const float* __restrict__ prods,
                                               const float* __restrict__ wgt,
                                               const float* __restrict__ T,
                                               float* __restrict__ out) {
    int h = blockIdx.x & 1;
    int c = (blockIdx.x >> 1) & (NC - 1);
    int b = blockIdx.x >> 7;
    int d = h * 256 + threadIdx.x;
    int bs0 = b * S + c * CL;

    float xv[CL];
#pragma unroll
    for (int i = 0; i < CL; ++i) xv[i] = x[(size_t)(bs0 + i) * D + d];

    float st[P];
    size_t tb = ((size_t)(b * NC + c)) * (P * D) + d;
#pragma unroll
    for (int p = 0; p < P; ++p) st[p] = T[tb + p * D];

#pragma unroll
    for (int i = 0; i < CL; ++i) {
        const int bs = bs0 + i;
        const float4* pp = (const float4*)(prods + (size_t)bs * P);
        const float4* wp = (const float4*)(wgt   + (size_t)bs * P);
        float pr[P], ww[P];
        ((float4*)pr)[0] = pp[0];
        ((float4*)pr)[1] = pp[1];
        ((float4*)pr)[2] = pp[2];
        ((float4*)pr)[3] = pp[3];
        ((float4*)ww)[0] = wp[0];
        ((float4*)ww)[1] = wp[1];
        ((float4*)ww)[2] = wp[2];
        ((float4*)ww)[3] = wp[3];
        float o = 0.f;
#pragma unroll
        for (int p = 0; p < P; ++p) {
            st[p] = fmaf(pr[p], xv[i], st[p]);
            o = fmaf(ww[p], st[p], o);
        }
        out[(size_t)bs * D + d] = o;
    }
}

extern "C" void kernel_launch(void* const* d_in, const int* in_sizes, int n_in,
                              void* d_out, int out_size, void* d_ws, size_t ws_size,
                              hipStream_t stream) {
    const float* x     = (const float*)d_in[0];
    const float* proxy = (const float*)d_in[1];
    float* out   = (float*)d_out;

    float* prods = (float*)d_ws;                 // B*S*P floats = 512 KiB
    float* wgt   = prods + (size_t)B * S * P;    // 512 KiB
    float* T     = wgt   + (size_t)B * S * P;    // B*NC*P*D floats = 8 MiB

    k_pt   <<<B * NC,             512, 0, stream>>>(x, proxy, prods, wgt, T);
    k_scan <<<(B * P * D) / 128,  128, 0, stream>>>(T);
    k_apply<<<B * NC * 2,         256, 0, stream>>>(x, prods, wgt, T, out);
}

// Round 6
// 45.174 us; speedup vs baseline: 1.2028x; 1.2028x over previous
//
#include <hip/hip_runtime.h>
#include <hip/hip_bf16.h>

#define B 4
#define S 2048
#define D 512
#define P 16
#define NC 64   // chunks over sequence
#define CL 32   // chunk length = S/NC

// ---------------------------------------------------------------------------
// K1: fused prods+softmax (phase A) and chunk totals (phase B).
// Block = (b,c), 512 threads.
// Phase A: R1-verbatim butterfly; wave wv owns rows 4wv..4wv+3; writes
//   prods/wgt to GLOBAL only (no LDS — preserve the fast path for phase B).
// Phase B: R1-verbatim k_totals body: thread = d, unroll 4, prods read as
//   block-uniform float4 loads -> compiler scalarizes to s_load (SGPR
//   broadcast operands, zero per-lane cost). x rows are L1-hot from phase A.
// ---------------------------------------------------------------------------
__global__ __launch_bounds__(512) void k_pt(const float* __restrict__ x,
                                            const float* __restrict__ proxy,
                                            float* __restrict__ prods,
                                            float* __restrict__ wgt,
                                            float* __restrict__ T) {
    const int c    = blockIdx.x & (NC - 1);
    const int b    = blockIdx.x >> 6;
    const int tid  = threadIdx.x;
    const int lane = tid & 63;
    const int wv   = tid >> 6;
    const int bs0  = b * S + c * CL;

    // ---------------- Phase A (R1 k_prods body, 4 rows per wave)
#pragma unroll
    for (int r = 0; r < 4; ++r) {
        const int bs = bs0 + wv * 4 + r;
        const float* xr = x + (size_t)bs * D + lane * 8;
        float4 xa = *(const float4*)xr;
        float4 xb = *(const float4*)(xr + 4);

        float part[P];
#pragma unroll
        for (int p = 0; p < P; ++p) {
            const float* pr = proxy + p * D + lane * 8;
            float4 pa = *(const float4*)pr;
            float4 pb = *(const float4*)(pr + 4);
            part[p] = xa.x*pa.x + xa.y*pa.y + xa.z*pa.z + xa.w*pa.w
                    + xb.x*pb.x + xb.y*pb.y + xb.z*pb.z + xb.w*pb.w;
        }
#pragma unroll
        for (int p = 0; p < P; ++p) {
            float v = part[p];
#pragma unroll
            for (int off = 32; off > 0; off >>= 1) v += __shfl_xor(v, off);
            part[p] = v;
        }
        float m = part[0];
#pragma unroll
        for (int p = 1; p < P; ++p) m = fmaxf(m, part[p]);
        float e[P];
        float den = 0.f;
#pragma unroll
        for (int p = 0; p < P; ++p) { e[p] = __expf((part[p] - m) * 0.25f); den += e[p]; }
        float inv = 1.f / den;

        int lp = lane & 15;
        float myp = part[0], mye = e[0];
#pragma unroll
        for (int p = 1; p < P; ++p) {
            bool sel = (lp == p);
            myp = sel ? part[p] : myp;
            mye = sel ? e[p]    : mye;
        }
        if (lane < P) {
            prods[(size_t)bs * P + lane] = myp;
            wgt  [(size_t)bs * P + lane] = mye * inv;
        }
    }
    __syncthreads();

    // ---------------- Phase B (R1 k_totals body, verbatim)
    {
        const int d = tid;
        float acc[P];
#pragma unroll
        for (int p = 0; p < P; ++p) acc[p] = 0.f;

#pragma unroll 4
        for (int i = 0; i < CL; ++i) {
            int bs = bs0 + i;
            float xv = x[(size_t)bs * D + d];
            const float4* pp = (const float4*)(prods + (size_t)bs * P);
            float pr[P];
            ((float4*)pr)[0] = pp[0];
            ((float4*)pr)[1] = pp[1];
            ((float4*)pr)[2] = pp[2];
            ((float4*)pr)[3] = pp[3];
#pragma unroll
            for (int p = 0; p < P; ++p) acc[p] = fmaf(pr[p], xv, acc[p]);
        }
        size_t tb = (size_t)blockIdx.x * (P * D) + d;
#pragma unroll
        for (int p = 0; p < P; ++p) T[tb + p * D] = acc[p];
    }
}

// ---------------------------------------------------------------------------
// K2: in-place exclusive prefix over chunks (R4 verbatim).
// ---------------------------------------------------------------------------
__global__ __launch_bounds__(256) void k_scan(float* __restrict__ T) {
    int t = blockIdx.x * blockDim.x + threadIdx.x;   // ((b*P+p)*D + d)
    int d = t & (D - 1);
    int p = (t >> 9) & (P - 1);
    int b = t >> 13;
    size_t base = ((size_t)b * NC * P + p) * D + d;
    float run = 0.f;
#pragma unroll 8
    for (int c = 0; c < NC; ++c) {
        size_t idx = base + (size_t)c * (P * D);
        float v = T[idx];
        T[idx] = run;
        run += v;
    }
}

// ---------------------------------------------------------------------------
// K3: apply (R4 verbatim). Block = (b,c,half), 256 threads, thread = d-half.
// ---------------------------------------------------------------------------
__global__ __launch_bounds__(256) void k_apply(const float* __restrict__ x,
                                               const float* __restrict__ prods,
                                               const float* __restrict__ wgt,
                                               const float* __restrict__ T,
                                               float* __restrict__ out) {
    int h = blockIdx.x & 1;
    int c = (blockIdx.x >> 1) & (NC - 1);
    int b = blockIdx.x >> 7;
    int d = h * 256 + threadIdx.x;

    float st[P];
    size_t tb = ((size_t)(b * NC + c)) * (P * D) + d;
#pragma unroll
    for (int p = 0; p < P; ++p) st[p] = T[tb + p * D];

    int bs0 = b * S + c * CL;
#pragma unroll 2
    for (int i = 0; i < CL; ++i) {
        int bs = bs0 + i;
        float xv = x[(size_t)bs * D + d];
        const float4* pp = (const float4*)(prods + (size_t)bs * P);
        const float4* wp = (const float4*)(wgt   + (size_t)bs * P);
        float pr[P], ww[P];
        ((float4*)pr)[0] = pp[0];
        ((float4*)pr)[1] = pp[1];
        ((float4*)pr)[2] = pp[2];
        ((float4*)pr)[3] = pp[3];
        ((float4*)ww)[0] = wp[0];
        ((float4*)ww)[1] = wp[1];
        ((float4*)ww)[2] = wp[2];
        ((float4*)ww)[3] = wp[3];
        float o = 0.f;
#pragma unroll
        for (int p = 0; p < P; ++p) {
            st[p] = fmaf(pr[p], xv, st[p]);
            o = fmaf(ww[p], st[p], o);
        }
        out[(size_t)bs * D + d] = o;
    }
}

extern "C" void kernel_launch(void* const* d_in, const int* in_sizes, int n_in,
                              void* d_out, int out_size, void* d_ws, size_t ws_size,
                              hipStream_t stream) {
    const float* x     = (const float*)d_in[0];
    const float* proxy = (const float*)d_in[1];
    float* out   = (float*)d_out;

    float* prods = (float*)d_ws;                 // B*S*P floats = 512 KiB
    float* wgt   = prods + (size_t)B * S * P;    // 512 KiB
    float* T     = wgt   + (size_t)B * S * P;    // B*NC*P*D floats = 8 MiB

    k_pt   <<<B * NC,             512, 0, stream>>>(x, proxy, prods, wgt, T);
    k_scan <<<(B * P * D) / 256,  256, 0, stream>>>(T);
    k_apply<<<B * NC * 2,         256, 0, stream>>>(x, prods, wgt, T, out);
}